// Round 4
// baseline (448.182 us; speedup 1.0000x reference)
//
#include <hip/hip_runtime.h>
#include <hip/hip_bf16.h>

// ---------------- problem constants ----------------
constexpr int kH = 1024, kS = 1024, kB = 2, kKD = 256, kNH = 16, kI = 4096, kNOUT = 2560;
constexpr int kQKVN = 1536;  // fused Q(1024)|K(256)|V(256) output width

typedef __attribute__((ext_vector_type(8))) short short8v;
typedef __attribute__((ext_vector_type(4))) float f32x4;

__device__ __forceinline__ unsigned short f2bf(float f) {
  unsigned u = __float_as_uint(f);
  return (unsigned short)((u + 0x7fffu + ((u >> 16) & 1u)) >> 16);
}
__device__ __forceinline__ float bf2f(unsigned short u) {
  return __uint_as_float(((unsigned)u) << 16);
}

// async global->LDS, 16B per lane. LDS dest is wave-uniform base (+lane*16 by HW).
__device__ __forceinline__ void gload16(void* lds, const void* g) {
  __builtin_amdgcn_global_load_lds(
      (const __attribute__((address_space(1))) unsigned int*)g,
      (__attribute__((address_space(3))) unsigned int*)lds, 16, 0, 0);
}

// ---------------- workspace layout (float offsets) ----------------
constexpr long OFF_H      = 0;                            // 2048x1024 f32
constexpr long OFF_HM     = OFF_H + 2097152;              // [2][1024]
constexpr long OFF_RS     = OFF_HM + 2048;                // B*NH*S
constexpr long OFF_INT    = OFF_RS + 32768;               // flag, sel[3], gate[6]
constexpr long OFF_GP     = OFF_INT + 64;                 // gate partial [64][1024]
constexpr long OFF_SLAB   = OFF_GP + 65536;               // 15,204,352 bf16
constexpr long OFF_WOUTBF = OFF_SLAB + 7602176;           // 2,621,440 bf16
constexpr long OFF_HBF    = OFF_WOUTBF + 1310720;         // 2M bf16
constexpr long OFF_QKV    = OFF_HBF + 1048576;            // 2048x1536 bf16
constexpr long OFF_ATT    = OFF_QKV + 1572864;            // 2048x1024 bf16
constexpr long OFF_OBF    = OFF_ATT + 1048576;            // 2048x1024 bf16
constexpr long OFF_PTMP   = OFF_OBF + 1048576;            // 2048x8192 bf16
constexpr long OFF_PBF    = OFF_PTMP + 8388608;           // 2048x4096 bf16

// slab offsets (bf16 elements): Wq|Wk|Wv contiguous (1536 rows), Wg|Wu contiguous (8192 rows)
constexpr long SB_WQ = 0, SB_WK = 1048576, SB_WV = 1310720, SB_WO = 1572864,
               SB_WG = 2621440, SB_WU = 6815744, SB_WD = 11010048, SB_TOT = 15204352;

// ---------------- prep: is_common flag ----------------
__global__ void prep_kernel(const int* __restrict__ ids, int* __restrict__ flag) {
  __shared__ int ok_s;
  if (threadIdx.x == 0) ok_s = 1;
  __syncthreads();
  int ok = 1;
  for (int i = threadIdx.x; i < kB * kS; i += blockDim.x) ok &= (ids[i] < 1000) ? 1 : 0;
  if (!ok) atomicAnd(&ok_s, 0);
  __syncthreads();
  if (threadIdx.x == 0) *flag = ok_s;
}

// ---------------- embedding gather (writes f32 h AND bf16 hbf) ----------------
__global__ void embed_kernel(const int* __restrict__ ids, const float* __restrict__ emb,
                             const float* __restrict__ semb, const int* __restrict__ flag,
                             float* __restrict__ h, unsigned short* __restrict__ hbf) {
  long row = blockIdx.x;
  int id = ids[row];
  int common = *flag;
  int cid = id; if (cid < 0) cid = 0; if (cid > 999) cid = 999;
  const float4* s4 = (const float4*)(common ? (semb + (long)cid * kH) : (emb + (long)id * kH));
  float4* d4 = (float4*)(h + row * kH);
  int i = threadIdx.x;
  float4 v = s4[i];
  d4[i] = v;
  ushort4 u;
  u.x = f2bf(v.x); u.y = f2bf(v.y); u.z = f2bf(v.z); u.w = f2bf(v.w);
  *(ushort4*)(hbf + row * kH + i * 4) = u;
}

// ---------------- hmean: per-batch column sums over s ----------------
__global__ void hmean2_kernel(const float* __restrict__ h, float* __restrict__ hm) {
  int b = blockIdx.y;
  int c = blockIdx.x * 256 + threadIdx.x;
  float a = 0.f;
  const float* p = h + ((long)b << 20) + c;
  for (int s = 0; s < kS; ++s) a += p[(long)s * kH];
  hm[b * kH + c] = a;
}

// ---------------- layer scores + top-3 selection (f32, batch 0) ----------------
__global__ void scores_kernel(const float* __restrict__ hm, const float* __restrict__ Wls,
                              const float* __restrict__ bls, int* __restrict__ sel) {
  int w = threadIdx.x >> 6, lane = threadIdx.x & 63;
  float acc = 0.f;
  if (w < 3) for (int c = lane; c < kH; c += 64) acc += hm[c] * Wls[w * kH + c];
  #pragma unroll
  for (int off = 32; off; off >>= 1) acc += __shfl_down(acc, off, 64);
  __shared__ float sc[3];
  if (w < 3 && lane == 0) sc[w] = acc * (1.f / kS) + bls[w];
  __syncthreads();
  if (threadIdx.x == 0) {
    int a = 0;
    if (sc[1] > sc[a]) a = 1;
    if (sc[2] > sc[a]) a = 2;
    int b2 = -1; float bb = -3.4e38f;
    for (int i = 0; i < 3; i++) if (i != a && sc[i] > bb) { bb = sc[i]; b2 = i; }
    sel[0] = a; sel[1] = b2; sel[2] = 3 - a - b2;
  }
}

// ---------------- gate part 1: partial[p][j] = sum_{c in block p} Wbs[c]*wq[c][j] --------
__global__ void gatevec_kernel(const float* __restrict__ Wq, const int* __restrict__ li_p,
                               const float* __restrict__ Wbs, float* __restrict__ partial) {
  int p = blockIdx.x;  // 64 blocks x 16 rows
  const float* wq = Wq + (long)(*li_p) * kH * kH + (long)p * 16 * kH;
  float acc[4] = {0.f, 0.f, 0.f, 0.f};
  for (int c = 0; c < 16; ++c) {
    float wb = Wbs[p * 16 + c];
    #pragma unroll
    for (int u = 0; u < 4; ++u)
      acc[u] += wb * wq[(long)c * kH + threadIdx.x + u * 256];
  }
  #pragma unroll
  for (int u = 0; u < 4; ++u) partial[(long)p * kH + threadIdx.x + u * 256] = acc[u];
}

// ---------------- gate part 2: g[b] = (dot(hm_b, v)/S + bbs > 0) ----------------
__global__ void gatefin_kernel(const float* __restrict__ hm, const float* __restrict__ partial,
                               const float* __restrict__ bbs, int* __restrict__ g) {
  float a0 = 0.f, a1 = 0.f;
  for (int j = threadIdx.x; j < kH; j += 256) {
    float v = 0.f;
    for (int p = 0; p < 64; ++p) v += partial[(long)p * kH + j];
    a0 += v * hm[j];
    a1 += v * hm[kH + j];
  }
  __shared__ float r0[4], r1[4];
  #pragma unroll
  for (int off = 32; off; off >>= 1) { a0 += __shfl_down(a0, off, 64); a1 += __shfl_down(a1, off, 64); }
  if ((threadIdx.x & 63) == 0) { r0[threadIdx.x >> 6] = a0; r1[threadIdx.x >> 6] = a1; }
  __syncthreads();
  if (threadIdx.x == 0) {
    float x0 = (r0[0] + r0[1] + r0[2] + r0[3]) * (1.f / kS) + bbs[0];
    float x1 = (r1[0] + r1[1] + r1[2] + r1[3]) * (1.f / kS) + bbs[0];
    g[0] = (x0 > 0.f) ? 1 : 0;
    g[1] = (x1 > 0.f) ? 1 : 0;
  }
}

// ---------------- weight conversion into per-layer bf16 slab ----------------
__global__ void wconv_kernel(const float* __restrict__ Wq, const float* __restrict__ Wk,
                             const float* __restrict__ Wv, const float* __restrict__ Wo,
                             const float* __restrict__ Wg, const float* __restrict__ Wu,
                             const float* __restrict__ Wd, const int* __restrict__ li_p,
                             const int* __restrict__ gate, unsigned short* __restrict__ slab) {
  if (!gate[0] && !gate[1]) return;
  long i = ((long)blockIdx.x * 256 + threadIdx.x) * 4;
  if (i >= SB_TOT) return;
  int li = *li_p;
  const float* src; long base, per;
  if      (i < SB_WK) { src = Wq; base = SB_WQ; per = 1048576; }
  else if (i < SB_WV) { src = Wk; base = SB_WK; per = 262144;  }
  else if (i < SB_WO) { src = Wv; base = SB_WV; per = 262144;  }
  else if (i < SB_WG) { src = Wo; base = SB_WO; per = 1048576; }
  else if (i < SB_WU) { src = Wg; base = SB_WG; per = 4194304; }
  else if (i < SB_WD) { src = Wu; base = SB_WU; per = 4194304; }
  else                { src = Wd; base = SB_WD; per = 4194304; }
  float4 v = *(const float4*)(src + (long)li * per + (i - base));
  ushort4 o;
  o.x = f2bf(v.x); o.y = f2bf(v.y); o.z = f2bf(v.z); o.w = f2bf(v.w);
  *(ushort4*)(slab + i) = o;
}

// ---------------- Wout -> bf16 (once) ----------------
__global__ void woutconv_kernel(const float* __restrict__ W, unsigned short* __restrict__ o) {
  long i = ((long)blockIdx.x * 256 + threadIdx.x) * 4;
  float4 v = *(const float4*)(W + i);
  ushort4 u;
  u.x = f2bf(v.x); u.y = f2bf(v.y); u.z = f2bf(v.z); u.w = f2bf(v.w);
  *(ushort4*)(o + i) = u;
}

// ---------------- bf16 MFMA GEMM: C = A @ B.T ----------------
// MODE 0: bf16 out. 1: f32 out. 2: f32 out C0 + bf16 out C1.
// BM=128, BN in {64,128}, BK=64, 4 waves (2m x BN/64... always 2x2), wave tile 64 x BN/2.
// Staging via global_load_lds: linear LDS dest, source column-chunk XOR pre-swizzle
// (c8^(r&7)); fragment reads use byte^((r&7)<<4)  => conflict-free b128.
template <int MODE, int BN>
__global__ __launch_bounds__(256) void gemm_bf_kernel(
    const unsigned short* __restrict__ A, const unsigned short* __restrict__ B0,
    void* __restrict__ C0, void* __restrict__ C1,
    int M, int N, int K, const int* __restrict__ gate) {
  constexpr int BM = 128, BK = 64;
  constexpr int WN = BN / 2;       // wave n-tile
  constexpr int NF = WN / 16;      // b-frags per wave (2 or 4)
  constexpr int BCH = BN / 32;     // B staging chunks per thread (2 or 4)
  __shared__ unsigned short As[BM * BK];
  __shared__ unsigned short Bs[BN * BK];

  const int m0 = blockIdx.y * BM, n0 = blockIdx.x * BN;
  if (gate != nullptr && !gate[m0 >> 10]) return;  // 128 | 1024: batch-pure blocks

  const int tid = threadIdx.x;
  const int wave = tid >> 6, lane = tid & 63;
  const int lr = lane & 15, lg = lane >> 4;
  const int wm = wave >> 1, wn = wave & 1;

  f32x4 acc[4][NF] = {};

  for (int k0 = 0; k0 < K; k0 += BK) {
    #pragma unroll
    for (int j = 0; j < 4; ++j) {
      int c = tid + j * 256;
      int r = c >> 3, c8 = c & 7;
      gload16((char*)As + (wave * 64 + j * 256) * 16,
              A + (long)(m0 + r) * K + k0 + ((c8 ^ (r & 7)) * 8));
    }
    #pragma unroll
    for (int j = 0; j < BCH; ++j) {
      int c = tid + j * 256;
      int r = c >> 3, c8 = c & 7;
      gload16((char*)Bs + (wave * 64 + j * 256) * 16,
              B0 + (long)(n0 + r) * K + k0 + ((c8 ^ (r & 7)) * 8));
    }
    __syncthreads();
    #pragma unroll
    for (int kh = 0; kh < 2; ++kh) {
      const int kb = kh * 64 + lg * 16;  // byte offset within a 128B row
      short8v a[4], b[NF];
      #pragma unroll
      for (int mi = 0; mi < 4; ++mi) {
        int r = wm * 64 + mi * 16 + lr;
        a[mi] = *(const short8v*)((const char*)As + ((r * 128 + kb) ^ ((r & 7) << 4)));
      }
      #pragma unroll
      for (int ni = 0; ni < NF; ++ni) {
        int r = wn * WN + ni * 16 + lr;
        b[ni] = *(const short8v*)((const char*)Bs + ((r * 128 + kb) ^ ((r & 7) << 4)));
      }
      #pragma unroll
      for (int mi = 0; mi < 4; ++mi)
        #pragma unroll
        for (int ni = 0; ni < NF; ++ni)
          acc[mi][ni] = __builtin_amdgcn_mfma_f32_16x16x32_bf16(a[mi], b[ni], acc[mi][ni], 0, 0, 0);
    }
    __syncthreads();
  }
  #pragma unroll
  for (int mi = 0; mi < 4; ++mi)
    #pragma unroll
    for (int ni = 0; ni < NF; ++ni)
      #pragma unroll
      for (int r = 0; r < 4; ++r) {
        long idx = (long)(m0 + wm * 64 + mi * 16 + lg * 4 + r) * N + (n0 + wn * WN + ni * 16 + lr);
        float v = acc[mi][ni][r];
        if constexpr (MODE == 0) ((unsigned short*)C0)[idx] = f2bf(v);
        if constexpr (MODE == 1) ((float*)C0)[idx] = v;
        if constexpr (MODE == 2) {
          ((float*)C0)[idx] = v;
          ((unsigned short*)C1)[idx] = f2bf(v);
        }
      }
}

// ---------------- rowsum of thresholded softmax via MFMA, 2 passes ----------------
// grid (S/64, NH, B), 256 thr = 4 waves x 16 q-rows. Q,K read from fused QKV buffer.
__global__ __launch_bounds__(256) void rowsum_mfma_kernel(
    const unsigned short* __restrict__ QKV, const int* __restrict__ gate,
    float* __restrict__ rs) {
  int b = blockIdx.z;
  if (gate && !gate[b]) return;
  int head = blockIdx.y, kv = head >> 2, qt = blockIdx.x;
  int wv = threadIdx.x >> 6, lane = threadIdx.x & 63;
  int lr = lane & 15, lg = lane >> 4;

  long qrow = ((long)b << 10) + qt * 64 + wv * 16 + lr;
  const unsigned short* qp = QKV + qrow * kQKVN + head * 64 + lg * 8;
  short8v qlo = *(const short8v*)qp;
  short8v qhi = *(const short8v*)(qp + 32);
  const unsigned short* kb = QKV + (((long)b << 10) + lr) * kQKVN + 1024 + kv * 64 + lg * 8;

  float m[4] = {-3e38f, -3e38f, -3e38f, -3e38f}, s[4] = {0.f, 0.f, 0.f, 0.f};
  for (int kt = 0; kt < 64; ++kt) {
    const unsigned short* kp = kb + (long)kt * 16 * kQKVN;
    short8v klo = *(const short8v*)kp;
    short8v khi = *(const short8v*)(kp + 32);
    f32x4 c = {0.f, 0.f, 0.f, 0.f};
    c = __builtin_amdgcn_mfma_f32_16x16x32_bf16(qlo, klo, c, 0, 0, 0);
    c = __builtin_amdgcn_mfma_f32_16x16x32_bf16(qhi, khi, c, 0, 0, 0);
    #pragma unroll
    for (int i = 0; i < 4; ++i) {
      float x = c[i] * 0.125f;
      float mn = fmaxf(m[i], x);
      s[i] = s[i] * __expf(m[i] - mn) + __expf(x - mn);
      m[i] = mn;
    }
  }
  #pragma unroll
  for (int off = 1; off < 16; off <<= 1) {
    #pragma unroll
    for (int i = 0; i < 4; ++i) {
      float mo = __shfl_xor(m[i], off);
      float so = __shfl_xor(s[i], off);
      float mn = fmaxf(m[i], mo);
      s[i] = s[i] * __expf(m[i] - mn) + so * __expf(mo - mn);
      m[i] = mn;
    }
  }
  float t[4] = {0.f, 0.f, 0.f, 0.f};
  for (int kt = 0; kt < 64; ++kt) {
    const unsigned short* kp = kb + (long)kt * 16 * kQKVN;
    short8v klo = *(const short8v*)kp;
    short8v khi = *(const short8v*)(kp + 32);
    f32x4 c = {0.f, 0.f, 0.f, 0.f};
    c = __builtin_amdgcn_mfma_f32_16x16x32_bf16(qlo, klo, c, 0, 0, 0);
    c = __builtin_amdgcn_mfma_f32_16x16x32_bf16(qhi, khi, c, 0, 0, 0);
    #pragma unroll
    for (int i = 0; i < 4; ++i) {
      float e = __expf(c[i] * 0.125f - m[i]);
      t[i] += (e > 0.01f * s[i]) ? e : 0.f;
    }
  }
  #pragma unroll
  for (int off = 1; off < 16; off <<= 1)
    #pragma unroll
    for (int i = 0; i < 4; ++i) t[i] += __shfl_xor(t[i], off);
  if (lr == 0) {
    long base = ((long)b * kNH + head) * kS + qt * 64 + wv * 16 + lg * 4;
    #pragma unroll
    for (int i = 0; i < 4; ++i) rs[base + i] = t[i] / s[i];
  }
}

// ---------------- attn = rowsum * V (bf16 out, V from QKV) ----------------
__global__ void attn_scale_bf_kernel(const unsigned short* __restrict__ QKV,
                                     const float* __restrict__ rs,
                                     const int* __restrict__ gate,
                                     unsigned short* __restrict__ Aout) {
  long row = blockIdx.x;
  int b = (int)(row >> 10);
  if (gate && !gate[b]) return;
  int s = (int)(row & (kS - 1));
  int c = threadIdx.x * 4;
  int head = c >> 6, kv = head >> 2, d = c & 63;
  float r = rs[((long)b * kNH + head) * kS + s];
  ushort4 v = *(const ushort4*)(QKV + row * kQKVN + 1280 + kv * 64 + d);
  ushort4 o;
  o.x = f2bf(r * bf2f(v.x)); o.y = f2bf(r * bf2f(v.y));
  o.z = f2bf(r * bf2f(v.z)); o.w = f2bf(r * bf2f(v.w));
  *(ushort4*)(Aout + row * kH + c) = o;
}

// ---------------- P = gate_half * up_half (elementwise from fused GU output) ----------
__global__ void pmul_kernel(const unsigned short* __restrict__ Ptmp,
                            const int* __restrict__ gate, unsigned short* __restrict__ P) {
  long row = blockIdx.x;
  if (!gate[(int)(row >> 10)]) return;
  int c = threadIdx.x * 16;
  const unsigned short* g = Ptmp + row * 8192 + c;
  const unsigned short* u = g + 4096;
  unsigned short o[16];
  #pragma unroll
  for (int j = 0; j < 16; ++j) o[j] = f2bf(bf2f(g[j]) * bf2f(u[j]));
  #pragma unroll
  for (int j = 0; j < 2; ++j)
    *(short8v*)(P + row * 4096 + c + j * 8) = *(short8v*)(o + j * 8);
}

// ---------------- launch ----------------
extern "C" void kernel_launch(void* const* d_in, const int* in_sizes, int n_in,
                              void* d_out, int out_size, void* d_ws, size_t ws_size,
                              hipStream_t stream) {
  (void)in_sizes; (void)n_in; (void)out_size; (void)ws_size;
  const int*   ids  = (const int*)d_in[0];
  const float* emb  = (const float*)d_in[1];
  const float* semb = (const float*)d_in[2];
  const float* Wq   = (const float*)d_in[3];
  const float* Wk   = (const float*)d_in[4];
  const float* Wv   = (const float*)d_in[5];
  const float* Wo   = (const float*)d_in[6];
  const float* Wg   = (const float*)d_in[7];
  const float* Wu   = (const float*)d_in[8];
  const float* Wd   = (const float*)d_in[9];
  const float* Wls  = (const float*)d_in[10];
  const float* bls  = (const float*)d_in[11];
  const float* Wbs  = (const float*)d_in[12];
  const float* bbs  = (const float*)d_in[13];
  const float* Wout = (const float*)d_in[14];
  float* out = (float*)d_out;
  float* ws  = (float*)d_ws;

  float* h   = ws + OFF_H;
  float* hm  = ws + OFF_HM;
  float* rs  = ws + OFF_RS;
  int* ip    = (int*)(ws + OFF_INT);
  int* flag  = ip;
  int* sel   = ip + 1;
  int* gate  = ip + 4;
  float* gp  = ws + OFF_GP;
  unsigned short* slab   = (unsigned short*)(ws + OFF_SLAB);
  unsigned short* woutbf = (unsigned short*)(ws + OFF_WOUTBF);
  unsigned short* hbf    = (unsigned short*)(ws + OFF_HBF);
  unsigned short* QKV    = (unsigned short*)(ws + OFF_QKV);
  unsigned short* ATT    = (unsigned short*)(ws + OFF_ATT);
  unsigned short* Obf    = (unsigned short*)(ws + OFF_OBF);
  unsigned short* Ptmp   = (unsigned short*)(ws + OFF_PTMP);
  unsigned short* Pbf    = (unsigned short*)(ws + OFF_PBF);

  const int M = kB * kS;  // 2048

  prep_kernel<<<1, 256, 0, stream>>>(ids, flag);
  embed_kernel<<<M, 256, 0, stream>>>(ids, emb, semb, flag, h, hbf);
  hmean2_kernel<<<dim3(kH / 256, kB), 256, 0, stream>>>(h, hm);
  scores_kernel<<<1, 192, 0, stream>>>(hm, Wls, bls, sel);
  woutconv_kernel<<<2560, 256, 0, stream>>>(Wout, woutbf);

  for (int i = 0; i < 3; i++) {
    const int* li = sel + i;
    int* g_i = gate + 2 * i;

    if (i > 0) hmean2_kernel<<<dim3(kH / 256, kB), 256, 0, stream>>>(h, hm);
    gatevec_kernel<<<64, 256, 0, stream>>>(Wq, li, Wbs, gp);
    gatefin_kernel<<<1, 256, 0, stream>>>(hm, gp, bbs, g_i);
    wconv_kernel<<<(int)(SB_TOT / 1024), 256, 0, stream>>>(Wq, Wk, Wv, Wo, Wg, Wu, Wd,
                                                           li, g_i, slab);
    // QKV = h @ [Wq|Wk|Wv].T (one GEMM, N=1536, gated)
    gemm_bf_kernel<0, 128><<<dim3(kQKVN / 128, M / 128), 256, 0, stream>>>(
        hbf, slab + SB_WQ, QKV, nullptr, M, kQKVN, kH, g_i);
    // rowsum of thresholded softmax; attn = rowsum * V
    rowsum_mfma_kernel<<<dim3(kS / 64, kNH, kB), 256, 0, stream>>>(QKV, g_i, rs);
    attn_scale_bf_kernel<<<M, 256, 0, stream>>>(QKV, rs, g_i, ATT);
    // O = attn @ wo.T (N=1024 -> BN=64 for full-grid coverage)
    gemm_bf_kernel<0, 64><<<dim3(kH / 64, M / 128), 256, 0, stream>>>(
        ATT, slab + SB_WO, Obf, nullptr, M, kH, kH, g_i);
    // GU = O @ [Wg|Wu].T (one GEMM, N=8192)
    gemm_bf_kernel<0, 128><<<dim3(2 * kI / 128, M / 128), 256, 0, stream>>>(
        Obf, slab + SB_WG, Ptmp, nullptr, M, 2 * kI, kH, g_i);
    // P = gate*up
    pmul_kernel<<<M, 256, 0, stream>>>(Ptmp, g_i, Pbf);
    // h = P @ wd.T -> f32 h + bf16 hbf (gated rows only)
    gemm_bf_kernel<2, 64><<<dim3(kH / 64, M / 128), 256, 0, stream>>>(
        Pbf, slab + SB_WD, h, hbf, M, kH, kI, g_i);
  }
  // out = h @ Wout[:2560].T (bf16 MFMA, f32 out)
  gemm_bf_kernel<1, 128><<<dim3(kNOUT / 128, M / 128), 256, 0, stream>>>(
      hbf, woutbf, out, nullptr, M, kNOUT, kH, nullptr);
}

// Round 5
// 302.058 us; speedup vs baseline: 1.4838x; 1.4838x over previous
//
#include <hip/hip_runtime.h>
#include <hip/hip_bf16.h>

// ---------------- problem constants ----------------
constexpr int kH = 1024, kS = 1024, kB = 2, kKD = 256, kNH = 16, kI = 4096, kNOUT = 2560;
constexpr int kQKVN = 1536;  // fused Q(1024)|K(256)|V(256) output width

typedef __attribute__((ext_vector_type(8))) short short8v;
typedef __attribute__((ext_vector_type(4))) float f32x4;

__device__ __forceinline__ unsigned short f2bf(float f) {
  unsigned u = __float_as_uint(f);
  return (unsigned short)((u + 0x7fffu + ((u >> 16) & 1u)) >> 16);
}
__device__ __forceinline__ float bf2f(unsigned short u) {
  return __uint_as_float(((unsigned)u) << 16);
}

// async global->LDS, 16B per lane. LDS dest is wave-uniform base (+lane*16 by HW).
__device__ __forceinline__ void gload16(void* lds, const void* g) {
  __builtin_amdgcn_global_load_lds(
      (const __attribute__((address_space(1))) unsigned int*)g,
      (__attribute__((address_space(3))) unsigned int*)lds, 16, 0, 0);
}

// ---------------- workspace layout (float offsets) ----------------
constexpr long OFF_H      = 0;                        // 2048x1024 f32
constexpr long OFF_HM     = OFF_H + 2097152;          // [2][1024]
constexpr long OFF_INT    = OFF_HM + 2048;            // flag, sel[3], gate[6], act[6]
constexpr long OFF_GP     = OFF_INT + 64;             // gate partial [3][64][1024]
constexpr long OFF_SLAB   = OFF_GP + 196608;          // 15,204,352 bf16
constexpr long OFF_WOUTBF = OFF_SLAB + 7602176;       // 2560x1024 bf16
constexpr long OFF_HBF    = OFF_WOUTBF + 1310720;     // 2048x1024 bf16
constexpr long OFF_QKV    = OFF_HBF + 1048576;        // 2048x1536 bf16
constexpr long OFF_ATT    = OFF_QKV + 1572864;        // 2048x1024 bf16
constexpr long OFF_OBF    = OFF_ATT + 1048576;        // 2048x1024 bf16
constexpr long OFF_PBF    = OFF_OBF + 1048576;        // 2048x4096 bf16

// slab offsets (bf16 elements): Wq|Wk|Wv contiguous (1536 rows), Wg & Wu at fixed bases
constexpr long SB_WQ = 0, SB_WK = 1048576, SB_WV = 1310720, SB_WO = 1572864,
               SB_WG = 2621440, SB_WU = 6815744, SB_WD = 11010048, SB_TOT = 15204352;

// ---------------- prep: is_common flag ----------------
__global__ void prep_kernel(const int* __restrict__ ids, int* __restrict__ flag) {
  __shared__ int ok_s;
  if (threadIdx.x == 0) ok_s = 1;
  __syncthreads();
  int ok = 1;
  for (int i = threadIdx.x; i < kB * kS; i += blockDim.x) ok &= (ids[i] < 1000) ? 1 : 0;
  if (!ok) atomicAnd(&ok_s, 0);
  __syncthreads();
  if (threadIdx.x == 0) *flag = ok_s;
}

// ---------------- embedding gather (writes f32 h AND bf16 hbf) ----------------
__global__ void embed_kernel(const int* __restrict__ ids, const float* __restrict__ emb,
                             const float* __restrict__ semb, const int* __restrict__ flag,
                             float* __restrict__ h, unsigned short* __restrict__ hbf) {
  long row = blockIdx.x;
  int id = ids[row];
  int common = *flag;
  int cid = id; if (cid < 0) cid = 0; if (cid > 999) cid = 999;
  const float4* s4 = (const float4*)(common ? (semb + (long)cid * kH) : (emb + (long)id * kH));
  float4* d4 = (float4*)(h + row * kH);
  int i = threadIdx.x;
  float4 v = s4[i];
  d4[i] = v;
  ushort4 u;
  u.x = f2bf(v.x); u.y = f2bf(v.y); u.z = f2bf(v.z); u.w = f2bf(v.w);
  *(ushort4*)(hbf + row * kH + i * 4) = u;
}

// ---------------- hmean: per-batch column sums over s ----------------
__global__ void hmean2_kernel(const float* __restrict__ h, float* __restrict__ hm) {
  int b = blockIdx.y;
  int c = blockIdx.x * 256 + threadIdx.x;
  float a = 0.f;
  const float* p = h + ((long)b << 20) + c;
  for (int s = 0; s < kS; ++s) a += p[(long)s * kH];
  hm[b * kH + c] = a;
}

// ---------------- layer scores + top-3 selection (f32, batch 0) ----------------
__global__ void scores_kernel(const float* __restrict__ hm, const float* __restrict__ Wls,
                              const float* __restrict__ bls, int* __restrict__ sel) {
  int w = threadIdx.x >> 6, lane = threadIdx.x & 63;
  float acc = 0.f;
  if (w < 3) for (int c = lane; c < kH; c += 64) acc += hm[c] * Wls[w * kH + c];
  #pragma unroll
  for (int off = 32; off; off >>= 1) acc += __shfl_down(acc, off, 64);
  __shared__ float sc[3];
  if (w < 3 && lane == 0) sc[w] = acc * (1.f / kS) + bls[w];
  __syncthreads();
  if (threadIdx.x == 0) {
    int a = 0;
    if (sc[1] > sc[a]) a = 1;
    if (sc[2] > sc[a]) a = 2;
    int b2 = -1; float bb = -3.4e38f;
    for (int i = 0; i < 3; i++) if (i != a && sc[i] > bb) { bb = sc[i]; b2 = i; }
    sel[0] = a; sel[1] = b2; sel[2] = 3 - a - b2;
  }
}

// ---------------- gate part 1 for ALL 3 selected layers ----------------
// gp[l][p][j] = sum_{c in 16-row block p} Wbs[c] * Wq[sel[l]][c][j]
__global__ void gatevec_kernel(const float* __restrict__ Wq, const int* __restrict__ sel,
                               const float* __restrict__ Wbs, float* __restrict__ gp) {
  int l = blockIdx.y, p = blockIdx.x;
  const float* wq = Wq + (long)sel[l] * kH * kH + (long)p * 16 * kH;
  float* partial = gp + (long)l * 65536 + (long)p * kH;
  float acc[4] = {0.f, 0.f, 0.f, 0.f};
  for (int c = 0; c < 16; ++c) {
    float wb = Wbs[p * 16 + c];
    #pragma unroll
    for (int u = 0; u < 4; ++u)
      acc[u] += wb * wq[(long)c * kH + threadIdx.x + u * 256];
  }
  #pragma unroll
  for (int u = 0; u < 4; ++u) partial[threadIdx.x + u * 256] = acc[u];
}

// ---------------- gate part 2: g[b] = (dot(hm_b, v)/S + bbs > 0); also reset act -------
__global__ void gatefin_kernel(const float* __restrict__ hm, const float* __restrict__ partial,
                               const float* __restrict__ bbs, int* __restrict__ g,
                               int* __restrict__ act) {
  float a0 = 0.f, a1 = 0.f;
  for (int j = threadIdx.x; j < kH; j += 256) {
    float v = 0.f;
    for (int p = 0; p < 64; ++p) v += partial[(long)p * kH + j];
    a0 += v * hm[j];
    a1 += v * hm[kH + j];
  }
  __shared__ float r0[4], r1[4];
  #pragma unroll
  for (int off = 32; off; off >>= 1) { a0 += __shfl_down(a0, off, 64); a1 += __shfl_down(a1, off, 64); }
  if ((threadIdx.x & 63) == 0) { r0[threadIdx.x >> 6] = a0; r1[threadIdx.x >> 6] = a1; }
  __syncthreads();
  if (threadIdx.x == 0) {
    float x0 = (r0[0] + r0[1] + r0[2] + r0[3]) * (1.f / kS) + bbs[0];
    float x1 = (r1[0] + r1[1] + r1[2] + r1[3]) * (1.f / kS) + bbs[0];
    g[0] = (x0 > 0.f) ? 1 : 0;
    g[1] = (x1 > 0.f) ? 1 : 0;
    act[0] = 0; act[1] = 0;
  }
}

// ---------------- weight conversion: Wq|Wk|Wv (needed pre-attention) ----------------
__global__ void wconvqkv_kernel(const float* __restrict__ Wq, const float* __restrict__ Wk,
                                const float* __restrict__ Wv, const int* __restrict__ li_p,
                                const int* __restrict__ gate, unsigned short* __restrict__ slab) {
  if (!gate[0] && !gate[1]) return;
  long i = ((long)blockIdx.x * 256 + threadIdx.x) * 4;  // grid 1536 -> covers SB_WO elems
  int li = *li_p;
  const float* src; long base, per;
  if      (i < SB_WK) { src = Wq; base = SB_WQ; per = 1048576; }
  else if (i < SB_WV) { src = Wk; base = SB_WK; per = 262144;  }
  else                { src = Wv; base = SB_WV; per = 262144;  }
  float4 v = *(const float4*)(src + (long)li * per + (i - base));
  ushort4 o;
  o.x = f2bf(v.x); o.y = f2bf(v.y); o.z = f2bf(v.z); o.w = f2bf(v.w);
  *(ushort4*)(slab + i) = o;
}

// ---------------- weight conversion: Wo|Wg|Wu|Wd (needed only when attention fired) ----
__global__ void wconvrest_kernel(const float* __restrict__ Wo, const float* __restrict__ Wg,
                                 const float* __restrict__ Wu, const float* __restrict__ Wd,
                                 const int* __restrict__ li_p, const int* __restrict__ gate,
                                 const int* __restrict__ act, unsigned short* __restrict__ slab) {
  if (!((gate[0] && act[0]) || (gate[1] && act[1]))) return;
  int li = *li_p;
  const long step = (long)gridDim.x * 256 * 4;
  for (long i = SB_WO + ((long)blockIdx.x * 256 + threadIdx.x) * 4; i < SB_TOT; i += step) {
    const float* src; long base, per;
    if      (i < SB_WG) { src = Wo; base = SB_WO; per = 1048576; }
    else if (i < SB_WU) { src = Wg; base = SB_WG; per = 4194304; }
    else if (i < SB_WD) { src = Wu; base = SB_WU; per = 4194304; }
    else                { src = Wd; base = SB_WD; per = 4194304; }
    float4 v = *(const float4*)(src + (long)li * per + (i - base));
    ushort4 o;
    o.x = f2bf(v.x); o.y = f2bf(v.y); o.z = f2bf(v.z); o.w = f2bf(v.w);
    *(ushort4*)(slab + i) = o;
  }
}

// ---------------- Wout -> bf16 (once) ----------------
__global__ void woutconv_kernel(const float* __restrict__ W, unsigned short* __restrict__ o) {
  long i = ((long)blockIdx.x * 256 + threadIdx.x) * 4;
  float4 v = *(const float4*)(W + i);
  ushort4 u;
  u.x = f2bf(v.x); u.y = f2bf(v.y); u.z = f2bf(v.z); u.w = f2bf(v.w);
  *(ushort4*)(o + i) = u;
}

// ---------------- bf16 MFMA GEMM: C = A @ B.T ----------------
// MODE 0: bf16 out. 1: f32 out. 2: f32 out C0 + bf16 out C1. 3: dual-B, bf16 out=acc0*acc1.
// BM=128, BN=64, BK=64, 4 waves (2m x 2n), wave tile 64x32.
// gate: per-batch skip. act: per-batch post-attention skip; ZFILL writes zero tile instead.
template <int MODE, bool ZFILL>
__global__ __launch_bounds__(256) void gemm_bf_kernel(
    const unsigned short* __restrict__ A, const unsigned short* __restrict__ B0,
    const unsigned short* __restrict__ B1, void* __restrict__ C0, void* __restrict__ C1,
    int M, int N, int K, const int* __restrict__ gate, const int* __restrict__ act) {
  constexpr bool USE_B1 = (MODE == 3);
  constexpr int BM = 128, BN = 64, BK = 64;
  __shared__ unsigned short As[BM * BK];
  __shared__ unsigned short Bs[BN * BK];
  __shared__ unsigned short Bs1[USE_B1 ? BN * BK : 8];

  const int m0 = blockIdx.y * BM, n0 = blockIdx.x * BN;
  const int tid = threadIdx.x;
  if (gate != nullptr) {
    int bb = m0 >> 10;  // 128 | 1024: batch-pure blocks
    if (!gate[bb]) return;
    if (act != nullptr && !act[bb]) {
      if constexpr (ZFILL) {  // new_h == 0 exactly: write zero f32 C0 + bf16 C1 tile
        int r = tid >> 1, cbase = n0 + (tid & 1) * 32;
        float4 z4 = make_float4(0.f, 0.f, 0.f, 0.f);
        ushort4 zu = {0, 0, 0, 0};
        float* c0 = (float*)C0 + (long)(m0 + r) * N + cbase;
        unsigned short* c1 = (unsigned short*)C1 + (long)(m0 + r) * N + cbase;
        #pragma unroll
        for (int j = 0; j < 32; j += 4) { *(float4*)(c0 + j) = z4; *(ushort4*)(c1 + j) = zu; }
      }
      return;
    }
  }

  const int wave = tid >> 6, lane = tid & 63;
  const int lr = lane & 15, lg = lane >> 4;
  const int wm = wave >> 1, wn = wave & 1;

  f32x4 acc[4][2] = {};
  f32x4 acc1[USE_B1 ? 4 : 1][2] = {};

  for (int k0 = 0; k0 < K; k0 += BK) {
    #pragma unroll
    for (int j = 0; j < 4; ++j) {
      int c = tid + j * 256;
      int r = c >> 3, c8 = c & 7;
      gload16((char*)As + (wave * 64 + j * 256) * 16,
              A + (long)(m0 + r) * K + k0 + ((c8 ^ (r & 7)) * 8));
    }
    #pragma unroll
    for (int j = 0; j < 2; ++j) {
      int c = tid + j * 256;
      int r = c >> 3, c8 = c & 7;
      long gb = (long)(n0 + r) * K + k0 + ((c8 ^ (r & 7)) * 8);
      gload16((char*)Bs + (wave * 64 + j * 256) * 16, B0 + gb);
      if constexpr (USE_B1)
        gload16((char*)Bs1 + (wave * 64 + j * 256) * 16, B1 + gb);
    }
    __syncthreads();
    #pragma unroll
    for (int kh = 0; kh < 2; ++kh) {
      const int kb = kh * 64 + lg * 16;
      short8v a[4], b[2], b1v[2];
      #pragma unroll
      for (int mi = 0; mi < 4; ++mi) {
        int r = wm * 64 + mi * 16 + lr;
        a[mi] = *(const short8v*)((const char*)As + ((r * 128 + kb) ^ ((r & 7) << 4)));
      }
      #pragma unroll
      for (int ni = 0; ni < 2; ++ni) {
        int r = wn * 32 + ni * 16 + lr;
        int byte = (r * 128 + kb) ^ ((r & 7) << 4);
        b[ni] = *(const short8v*)((const char*)Bs + byte);
        if constexpr (USE_B1) b1v[ni] = *(const short8v*)((const char*)Bs1 + byte);
      }
      #pragma unroll
      for (int mi = 0; mi < 4; ++mi)
        #pragma unroll
        for (int ni = 0; ni < 2; ++ni) {
          acc[mi][ni] = __builtin_amdgcn_mfma_f32_16x16x32_bf16(a[mi], b[ni], acc[mi][ni], 0, 0, 0);
          if constexpr (USE_B1)
            acc1[mi][ni] = __builtin_amdgcn_mfma_f32_16x16x32_bf16(a[mi], b1v[ni], acc1[mi][ni], 0, 0, 0);
        }
    }
    __syncthreads();
  }
  #pragma unroll
  for (int mi = 0; mi < 4; ++mi)
    #pragma unroll
    for (int ni = 0; ni < 2; ++ni)
      #pragma unroll
      for (int r = 0; r < 4; ++r) {
        long idx = (long)(m0 + wm * 64 + mi * 16 + lg * 4 + r) * N + (n0 + wn * 32 + ni * 16 + lr);
        float v = acc[mi][ni][r];
        if constexpr (MODE == 0) ((unsigned short*)C0)[idx] = f2bf(v);
        if constexpr (MODE == 1) ((float*)C0)[idx] = v;
        if constexpr (MODE == 2) {
          ((float*)C0)[idx] = v;
          ((unsigned short*)C1)[idx] = f2bf(v);
        }
        if constexpr (MODE == 3) ((unsigned short*)C0)[idx] = f2bf(v * acc1[mi][ni][r]);
      }
}

// ---------------- rowsum of thresholded softmax + fused attn = rs*V ----------------
// grid (S/16, NH, B), 256 thr = 4 waves; each wave covers a 256-k-row quarter; the
// block's 16 q-rows are shared. Online softmax stats merged across waves via LDS.
// Writes ATT tile [16 x 64] and sets act[b] if any thresholded mass survives.
__global__ __launch_bounds__(256) void rowsum_fused_kernel(
    const unsigned short* __restrict__ QKV, const int* __restrict__ gate,
    int* __restrict__ act, unsigned short* __restrict__ ATT) {
  int b = blockIdx.z;
  if (!gate[b]) return;
  int head = blockIdx.y, kv = head >> 2, qt = blockIdx.x;
  int w = threadIdx.x >> 6, lane = threadIdx.x & 63;
  int lr = lane & 15, lg = lane >> 4;

  long qrow = ((long)b << 10) + qt * 16 + lr;
  const unsigned short* qp = QKV + qrow * kQKVN + head * 64 + lg * 8;
  short8v qlo = *(const short8v*)qp;
  short8v qhi = *(const short8v*)(qp + 32);
  const unsigned short* kb =
      QKV + (((long)b << 10) + w * 256 + lr) * kQKVN + 1024 + kv * 64 + lg * 8;

  // pass 1: online max + denominator over this wave's 256 k-rows
  float m[4] = {-3e38f, -3e38f, -3e38f, -3e38f}, s[4] = {0.f, 0.f, 0.f, 0.f};
  for (int kt = 0; kt < 16; ++kt) {
    const unsigned short* kp = kb + (long)kt * 16 * kQKVN;
    short8v klo = *(const short8v*)kp;
    short8v khi = *(const short8v*)(kp + 32);
    f32x4 c = {0.f, 0.f, 0.f, 0.f};
    c = __builtin_amdgcn_mfma_f32_16x16x32_bf16(qlo, klo, c, 0, 0, 0);
    c = __builtin_amdgcn_mfma_f32_16x16x32_bf16(qhi, khi, c, 0, 0, 0);
    #pragma unroll
    for (int i = 0; i < 4; ++i) {
      float x = c[i] * 0.125f;
      float mn = fmaxf(m[i], x);
      s[i] = s[i] * __expf(m[i] - mn) + __expf(x - mn);
      m[i] = mn;
    }
  }
  #pragma unroll
  for (int off = 1; off < 16; off <<= 1) {
    #pragma unroll
    for (int i = 0; i < 4; ++i) {
      float mo = __shfl_xor(m[i], off);
      float so = __shfl_xor(s[i], off);
      float mn = fmaxf(m[i], mo);
      s[i] = s[i] * __expf(m[i] - mn) + so * __expf(mo - mn);
      m[i] = mn;
    }
  }
  __shared__ float smx[4][16], ssm[4][16], stt[4][16], sS[16], srs[16];
  if (lr == 0) {
    #pragma unroll
    for (int i = 0; i < 4; ++i) { smx[w][lg * 4 + i] = m[i]; ssm[w][lg * 4 + i] = s[i]; }
  }
  __syncthreads();
  float M[4], S[4];
  #pragma unroll
  for (int i = 0; i < 4; ++i) {
    int q = lg * 4 + i;
    float mm = fmaxf(fmaxf(smx[0][q], smx[1][q]), fmaxf(smx[2][q], smx[3][q]));
    S[i] = ssm[0][q] * __expf(smx[0][q] - mm) + ssm[1][q] * __expf(smx[1][q] - mm) +
           ssm[2][q] * __expf(smx[2][q] - mm) + ssm[3][q] * __expf(smx[3][q] - mm);
    M[i] = mm;
  }
  // pass 2: thresholded sum (e > 0.01*S  <=>  aw > 0.01)
  float t[4] = {0.f, 0.f, 0.f, 0.f};
  for (int kt = 0; kt < 16; ++kt) {
    const unsigned short* kp = kb + (long)kt * 16 * kQKVN;
    short8v klo = *(const short8v*)kp;
    short8v khi = *(const short8v*)(kp + 32);
    f32x4 c = {0.f, 0.f, 0.f, 0.f};
    c = __builtin_amdgcn_mfma_f32_16x16x32_bf16(qlo, klo, c, 0, 0, 0);
    c = __builtin_amdgcn_mfma_f32_16x16x32_bf16(qhi, khi, c, 0, 0, 0);
    #pragma unroll
    for (int i = 0; i < 4; ++i) {
      float e = __expf(c[i] * 0.125f - M[i]);
      t[i] += (e > 0.01f * S[i]) ? e : 0.f;
    }
  }
  #pragma unroll
  for (int off = 1; off < 16; off <<= 1)
    #pragma unroll
    for (int i = 0; i < 4; ++i) t[i] += __shfl_xor(t[i], off);
  if (lr == 0) {
    #pragma unroll
    for (int i = 0; i < 4; ++i) stt[w][lg * 4 + i] = t[i];
    if (w == 0) {
      #pragma unroll
      for (int i = 0; i < 4; ++i) sS[lg * 4 + i] = S[i];
    }
  }
  __syncthreads();
  if (threadIdx.x < 16) {
    float T = stt[0][threadIdx.x] + stt[1][threadIdx.x] + stt[2][threadIdx.x] + stt[3][threadIdx.x];
    srs[threadIdx.x] = T / sS[threadIdx.x];
    if (T > 0.f) atomicOr(&act[b], 1);
  }
  __syncthreads();
  // fused attn write: ATT[row][head*64 + d] = rs * V[row][kv*64 + d]
  int rr = threadIdx.x >> 4, d = (threadIdx.x & 15) * 4;
  float rv = srs[rr];
  long row = ((long)b << 10) + qt * 16 + rr;
  ushort4 v = *(const ushort4*)(QKV + row * kQKVN + 1280 + kv * 64 + d);
  ushort4 o;
  o.x = f2bf(rv * bf2f(v.x)); o.y = f2bf(rv * bf2f(v.y));
  o.z = f2bf(rv * bf2f(v.z)); o.w = f2bf(rv * bf2f(v.w));
  *(ushort4*)(ATT + row * kH + head * 64 + d) = o;
}

// ---------------- launch ----------------
extern "C" void kernel_launch(void* const* d_in, const int* in_sizes, int n_in,
                              void* d_out, int out_size, void* d_ws, size_t ws_size,
                              hipStream_t stream) {
  (void)in_sizes; (void)n_in; (void)out_size; (void)ws_size;
  const int*   ids  = (const int*)d_in[0];
  const float* emb  = (const float*)d_in[1];
  const float* semb = (const float*)d_in[2];
  const float* Wq   = (const float*)d_in[3];
  const float* Wk   = (const float*)d_in[4];
  const float* Wv   = (const float*)d_in[5];
  const float* Wo   = (const float*)d_in[6];
  const float* Wg   = (const float*)d_in[7];
  const float* Wu   = (const float*)d_in[8];
  const float* Wd   = (const float*)d_in[9];
  const float* Wls  = (const float*)d_in[10];
  const float* bls  = (const float*)d_in[11];
  const float* Wbs  = (const float*)d_in[12];
  const float* bbs  = (const float*)d_in[13];
  const float* Wout = (const float*)d_in[14];
  float* out = (float*)d_out;
  float* ws  = (float*)d_ws;

  float* h   = ws + OFF_H;
  float* hm  = ws + OFF_HM;
  int* ip    = (int*)(ws + OFF_INT);
  int* flag  = ip;
  int* sel   = ip + 1;
  int* gate  = ip + 4;
  int* act   = ip + 10;
  float* gp  = ws + OFF_GP;
  unsigned short* slab   = (unsigned short*)(ws + OFF_SLAB);
  unsigned short* woutbf = (unsigned short*)(ws + OFF_WOUTBF);
  unsigned short* hbf    = (unsigned short*)(ws + OFF_HBF);
  unsigned short* QKV    = (unsigned short*)(ws + OFF_QKV);
  unsigned short* ATT    = (unsigned short*)(ws + OFF_ATT);
  unsigned short* Obf    = (unsigned short*)(ws + OFF_OBF);
  unsigned short* Pbf    = (unsigned short*)(ws + OFF_PBF);

  const int M = kB * kS;  // 2048

  prep_kernel<<<1, 256, 0, stream>>>(ids, flag);
  embed_kernel<<<M, 256, 0, stream>>>(ids, emb, semb, flag, h, hbf);
  hmean2_kernel<<<dim3(kH / 256, kB), 256, 0, stream>>>(h, hm);
  scores_kernel<<<1, 192, 0, stream>>>(hm, Wls, bls, sel);
  woutconv_kernel<<<2560, 256, 0, stream>>>(Wout, woutbf);
  gatevec_kernel<<<dim3(64, 3), 256, 0, stream>>>(Wq, sel, Wbs, gp);

  for (int i = 0; i < 3; i++) {
    const int* li = sel + i;
    int* g_i = gate + 2 * i;
    int* a_i = act + 2 * i;

    if (i > 0) hmean2_kernel<<<dim3(kH / 256, kB), 256, 0, stream>>>(h, hm);
    gatefin_kernel<<<1, 256, 0, stream>>>(hm, gp + (long)i * 65536, bbs, g_i, a_i);
    wconvqkv_kernel<<<1536, 256, 0, stream>>>(Wq, Wk, Wv, li, g_i, slab);
    // QKV = h @ [Wq|Wk|Wv].T (gated)
    gemm_bf_kernel<0, false><<<dim3(kQKVN / 64, M / 128), 256, 0, stream>>>(
        hbf, slab + SB_WQ, nullptr, QKV, nullptr, M, kQKVN, kH, g_i, nullptr);
    // thresholded-softmax rowsum + attn = rs*V (sets act)
    rowsum_fused_kernel<<<dim3(kS / 16, kNH, kB), 256, 0, stream>>>(QKV, g_i, a_i, ATT);
    // remaining weights only needed if some batch is gated AND has live attention
    wconvrest_kernel<<<2048, 256, 0, stream>>>(Wo, Wg, Wu, Wd, li, g_i, a_i, slab);
    // O = attn @ wo.T
    gemm_bf_kernel<0, false><<<dim3(kH / 64, M / 128), 256, 0, stream>>>(
        ATT, slab + SB_WO, nullptr, Obf, nullptr, M, kH, kH, g_i, a_i);
    // P = (O @ wg.T) * (O @ wu.T)  (dual-B)
    gemm_bf_kernel<3, false><<<dim3(kI / 64, M / 128), 256, 0, stream>>>(
        Obf, slab + SB_WG, slab + SB_WU, Pbf, nullptr, M, kI, kH, g_i, a_i);
    // h = P @ wd.T -> f32 h + bf16 hbf; zero-fill when attention fully thresholded out
    gemm_bf_kernel<2, true><<<dim3(kH / 64, M / 128), 256, 0, stream>>>(
        Pbf, slab + SB_WD, nullptr, h, hbf, M, kH, kI, g_i, a_i);
  }
  // out = h @ Wout[:2560].T (bf16 MFMA, f32 out)
  gemm_bf_kernel<1, false><<<dim3(kNOUT / 64, M / 128), 256, 0, stream>>>(
      hbf, woutbf, nullptr, out, nullptr, M, kNOUT, kH, nullptr, nullptr);
}